// Round 2
// baseline (914.129 us; speedup 1.0000x reference)
//
#include <hip/hip_runtime.h>
#include <math.h>

// SpectralNorm: sigma = max(1, s_max(w2d)/2); w = w_bar/sigma; conv3x3 pad1 + bias.
// x: [32,32,256,256] f32, w_bar: [32,32,3,3] f32, bias: [32] f32, out: [32,32,256,256] f32.

// ---------------- prep: sigma via G = W W^T, squaring + power iter ----------------
__global__ __launch_bounds__(256) void sn_prep_kernel(
    const float* __restrict__ w_bar,   // [32][288] row-major (k major)
    float* __restrict__ w_out)         // [288][32]: [(c*9+q)][k], scaled by 1/sigma
{
  __shared__ __align__(16) float sw[9216];    // [k][t]
  __shared__ __align__(16) float swT[9216];   // [t][k]
  __shared__ float G0[1024];
  __shared__ float Gpp[2048];                 // ping-pong pair, indexed at runtime
  __shared__ float vvec[32];
  __shared__ float svec[32];
  __shared__ float scal[2];
  const int tid = threadIdx.x;

  for (int i = tid; i < 9216; i += 256) {
    float v = w_bar[i];
    sw[i] = v;
    int k = i / 288;
    int t = i - k * 288;
    swT[t * 32 + k] = v;   // conflict-free lane-stride-1 reads later
  }
  __syncthreads();

  // G[i][j] = dot(row i, row j) over 288
  for (int e = tid; e < 1024; e += 256) {
    int i = e >> 5, j = e & 31;
    const float* ri = &sw[i * 288];
    float s = 0.f;
    for (int t = 0; t < 288; t += 4) {
      float4 a = *(const float4*)(ri + t);
      s = fmaf(a.x, swT[(t + 0) * 32 + j], s);
      s = fmaf(a.y, swT[(t + 1) * 32 + j], s);
      s = fmaf(a.z, swT[(t + 2) * 32 + j], s);
      s = fmaf(a.w, swT[(t + 3) * 32 + j], s);
    }
    G0[e] = s;
  }

  // 6 normalized squarings -> direction of G^64 (scale irrelevant, renorm avoids overflow)
  const float* src = G0;
  for (int sq = 0; sq < 6; ++sq) {
    float* dst = &Gpp[(sq & 1) * 1024];
    __syncthreads();
    for (int e = tid; e < 1024; e += 256) {
      int i = e >> 5, j = e & 31;
      float s = 0.f;
#pragma unroll
      for (int t = 0; t < 32; ++t)
        s = fmaf(src[i * 32 + t], src[t * 32 + j], s);
      dst[e] = s;
    }
    __syncthreads();
    float s0 = dst[0];
    float inv = (s0 > 0.f) ? (1.f / s0) : 1.f;
    __syncthreads();
    for (int e = tid; e < 1024; e += 256) dst[e] *= inv;
    src = dst;
  }

  // power iterations on G^64, then Rayleigh quotient with original G0
  if (tid < 32) vvec[tid] = 1.f;
  __syncthreads();
  for (int it = 0; it < 4; ++it) {
    if (tid < 32) {
      float s = 0.f;
#pragma unroll
      for (int j = 0; j < 32; ++j) s = fmaf(src[tid * 32 + j], vvec[j], s);
      svec[tid] = s;
    }
    __syncthreads();
    if (tid == 0) {
      float n2 = 0.f;
      for (int j = 0; j < 32; ++j) n2 += svec[j] * svec[j];
      scal[0] = (n2 > 0.f) ? rsqrtf(n2) : 0.f;
    }
    __syncthreads();
    if (tid < 32) vvec[tid] = svec[tid] * scal[0];
    __syncthreads();
  }

  if (tid < 32) {
    float s = 0.f;
#pragma unroll
    for (int j = 0; j < 32; ++j) s = fmaf(G0[tid * 32 + j], vvec[j], s);
    svec[tid] = s * vvec[tid];
  }
  __syncthreads();
  if (tid == 0) {
    float lam = 0.f;
    for (int j = 0; j < 32; ++j) lam += svec[j];
    lam = fmaxf(lam, 0.f);
    float sigma = fmaxf(1.f, 0.5f * sqrtf(lam));
    scal[1] = 1.f / sigma;
  }
  __syncthreads();
  float inv_sigma = scal[1];
  for (int e = tid; e < 9216; e += 256)
    w_out[e] = swT[e] * inv_sigma;   // already [t][k] layout
}

// ---------------- conv: 3x3 pad1, direct, fp32 ----------------
// Block: 256 thr. Tile: n fixed, 8 rows x 64 cols, all 32 k.
// Thread: k = tid&31, xg = tid>>5 -> 8x8 output patch, 64 accumulators.
__global__ __launch_bounds__(256, 2) void sn_conv_kernel(
    const float* __restrict__ x, const float* __restrict__ wS,
    const float* __restrict__ bias, float* __restrict__ out)
{
  __shared__ __align__(16) float sw[9216];      // [c][9][k] -> lane-stride-1 in k
  __shared__ __align__(16) float sx[4][10][68]; // 4 chans, 10 rows, 66 cols (+pad)
  const int tid = threadIdx.x;
  const int n  = blockIdx.z;
  const int y0 = blockIdx.y * 8;
  const int x0 = blockIdx.x * 64;
  const int k  = tid & 31;
  const int xg = tid >> 5;
  const int xb = xg * 8;

  for (int i = tid; i < 9216; i += 256) sw[i] = wS[i];
  float b = bias[k];
  float acc[8][8];
#pragma unroll
  for (int r = 0; r < 8; ++r)
#pragma unroll
    for (int q = 0; q < 8; ++q) acc[r][q] = b;

  for (int c0 = 0; c0 < 32; c0 += 4) {
    __syncthreads();
    for (int idx = tid; idx < 4 * 10 * 66; idx += 256) {
      int cl  = idx / 660;
      int rem = idx - cl * 660;
      int r   = rem / 66;
      int col = rem - r * 66;
      int gy = y0 - 1 + r;
      int gx = x0 - 1 + col;
      float v = 0.f;
      if ((unsigned)gy < 256u && (unsigned)gx < 256u)
        v = x[((n * 32 + c0 + cl) * 256 + gy) * 256 + gx];
      sx[cl][r][col] = v;
    }
    __syncthreads();
    for (int cl = 0; cl < 4; ++cl) {
      const int c = c0 + cl;
      float wr[9];
#pragma unroll
      for (int q = 0; q < 9; ++q) wr[q] = sw[(c * 9 + q) * 32 + k];
#pragma unroll
      for (int r = 0; r < 10; ++r) {
        const float* row = &sx[cl][r][xb];   // xb is 8-aligned, row stride 272B
        float4 p0 = *(const float4*)(row);
        float4 p1 = *(const float4*)(row + 4);
        float2 p2 = *(const float2*)(row + 8);
        float win[10] = {p0.x, p0.y, p0.z, p0.w, p1.x, p1.y, p1.z, p1.w, p2.x, p2.y};
#pragma unroll
        for (int dy = 0; dy < 3; ++dy) {
          const int yo = r - dy;             // input row r feeds output row r-dy
          if (yo >= 0 && yo < 8) {
#pragma unroll
            for (int xo = 0; xo < 8; ++xo) {
              acc[yo][xo] = fmaf(win[xo + 0], wr[dy * 3 + 0], acc[yo][xo]);
              acc[yo][xo] = fmaf(win[xo + 1], wr[dy * 3 + 1], acc[yo][xo]);
              acc[yo][xo] = fmaf(win[xo + 2], wr[dy * 3 + 2], acc[yo][xo]);
            }
          }
        }
      }
    }
  }

  const int gx = x0 + xb;
#pragma unroll
  for (int r = 0; r < 8; ++r) {
    float* dst = &out[((n * 32 + k) * 256 + (y0 + r)) * 256 + gx];
    *(float4*)(dst)     = make_float4(acc[r][0], acc[r][1], acc[r][2], acc[r][3]);
    *(float4*)(dst + 4) = make_float4(acc[r][4], acc[r][5], acc[r][6], acc[r][7]);
  }
}

extern "C" void kernel_launch(void* const* d_in, const int* in_sizes, int n_in,
                              void* d_out, int out_size, void* d_ws, size_t ws_size,
                              hipStream_t stream) {
  (void)in_sizes; (void)n_in; (void)out_size; (void)ws_size;
  const float* x     = (const float*)d_in[0];
  const float* w_bar = (const float*)d_in[1];
  const float* bias  = (const float*)d_in[2];
  float* out = (float*)d_out;
  float* wS  = (float*)d_ws;   // 9216 floats = 36 KB scratch

  sn_prep_kernel<<<1, 256, 0, stream>>>(w_bar, wS);
  dim3 grid(256 / 64, 256 / 8, 32);   // (x-tiles, y-tiles, n)
  sn_conv_kernel<<<grid, 256, 0, stream>>>(x, wS, bias, out);
}